// Round 3
// baseline (90.164 us; speedup 1.0000x reference)
//
#include <hip/hip_runtime.h>
#include <stdint.h>

#define PP     16
#define LRDIM  256
#define DDIM   1024
#define LN_EPS 1e-5f

typedef __attribute__((ext_vector_type(8))) short  short8;
typedef __attribute__((ext_vector_type(4))) float  f32x4;

__device__ __forceinline__ uint32_t bf16_rne(float f) {
    uint32_t u = __builtin_bit_cast(uint32_t, f);
    return (u + 0x7fffu + ((u >> 16) & 1u)) >> 16;
}
__device__ __forceinline__ float bf_lo(uint32_t u) {
    return __builtin_bit_cast(float, u << 16);
}
__device__ __forceinline__ float bf_hi(uint32_t u) {
    return __builtin_bit_cast(float, u & 0xffff0000u);
}

// ---------------------------------------------------------------------------
// K1 fused prep.
// blocks [0,512):  table2b[p][c][j] = bf16(sum_i pe[p][i][j] * bt[c][i]),
//                  8 c-rows per block  (p = bx>>5, c0 = (bx&31)*8)
// blocks [512,640): repack W_up [D][LR] f32 -> bf16 MFMA B-fragments:
//                  wb[(nfg*8+ks)*64+lane] = W[nfg*16+(l&15)][ks*32+(l>>4)*8+..7]
// ---------------------------------------------------------------------------
__global__ __launch_bounds__(256) void k_prep(const float* __restrict__ bt,
                                              const float* __restrict__ pe,
                                              const float* __restrict__ W,
                                              unsigned short* __restrict__ t2b,
                                              uint4* __restrict__ wb) {
    if (blockIdx.x < 512) {
        const int p  = blockIdx.x >> 5;          // 0..15
        const int c0 = (blockIdx.x & 31) << 3;   // 0..248
        const int j  = threadIdx.x;
        const float* pep = pe + (size_t)p * LRDIM * LRDIM;
        float a[8];
#pragma unroll
        for (int r = 0; r < 8; ++r) a[r] = 0.f;
#pragma unroll 4
        for (int i = 0; i < LRDIM; ++i) {
            const float v = pep[i * LRDIM + j];          // coalesced across j
#pragma unroll
            for (int r = 0; r < 8; ++r)                   // uniform -> s_loads
                a[r] = fmaf(v, bt[(c0 + r) * LRDIM + i], a[r]);
        }
#pragma unroll
        for (int r = 0; r < 8; ++r)
            t2b[(size_t)((p << 8) + c0 + r) * LRDIM + j] =
                (unsigned short)bf16_rne(a[r]);
    } else {
        const int gt  = (blockIdx.x - 512) * 256 + threadIdx.x;  // 0..32767
        const int l   = gt & 63;
        const int ks  = (gt >> 6) & 7;
        const int nfg = gt >> 9;                                  // 0..63
        const int n   = nfg * 16 + (l & 15);
        const int k   = ks * 32 + (l >> 4) * 8;
        const float* src = W + (size_t)n * LRDIM + k;
        uint32_t r[4];
#pragma unroll
        for (int q = 0; q < 4; ++q) {
            const uint32_t lo = bf16_rne(src[2 * q + 0]);
            const uint32_t hi = bf16_rne(src[2 * q + 1]);
            r[q] = lo | (hi << 16);
        }
        wb[gt] = make_uint4(r[0], r[1], r[2], r[3]);
    }
}

// ---------------------------------------------------------------------------
// K2: gather-sum. One wave per token; lane owns lr = 4l..4l+3.
// A[tok][256] bf16 out (uint2 per lane). 16 independent masked loads/lane.
// ---------------------------------------------------------------------------
__global__ __launch_bounds__(256) void k_gather(const int* __restrict__ ids,
                                                const unsigned short* __restrict__ t2b,
                                                uint2* __restrict__ Aq,
                                                int ntok) {
    const int wid = (blockIdx.x << 2) + (threadIdx.x >> 6);
    const int l   = threadIdx.x & 63;
    if (wid >= ntok) return;

    const int myid = (l < PP) ? ids[(size_t)wid * PP + l] : -1;

    float a0 = 0.f, a1 = 0.f, a2 = 0.f, a3 = 0.f;
#pragma unroll
    for (int p = 0; p < PP; ++p) {
        const int   id  = __shfl(myid, p);
        const float msk = (id >= 0) ? 1.f : 0.f;
        const uint2 v = *(const uint2*)(t2b +
                          ((size_t)((p << 8) + (id & 255)) << 8) + (l << 2));
        a0 = fmaf(msk, bf_lo(v.x), a0);
        a1 = fmaf(msk, bf_hi(v.x), a1);
        a2 = fmaf(msk, bf_lo(v.y), a2);
        a3 = fmaf(msk, bf_hi(v.y), a3);
    }
    uint2 pk;
    pk.x = bf16_rne(a0) | (bf16_rne(a1) << 16);
    pk.y = bf16_rne(a2) | (bf16_rne(a3) << 16);
    Aq[(size_t)wid * 64 + l] = pk;
}

// ---------------------------------------------------------------------------
// K3: barrier-free MFMA GEMM + fused bias/LN.
// Block = 512 thr (8 waves), 32 tokens x N=1024. Wave w owns N-slice
// [w*128, w*128+128): acc[m2][nf] = 2 x 8 f32x4 (64 VGPR).
// A-fragments loaded straight from global (L2); B from prepacked wb (L2).
// Only one barrier (LN cross-wave reduce).
// ---------------------------------------------------------------------------
__global__ __launch_bounds__(512, 4) void k_gemm(const unsigned short* __restrict__ A,
                                                 const uint4* __restrict__ wb,
                                                 const float* __restrict__ b_up,
                                                 const float* __restrict__ gamma,
                                                 const float* __restrict__ beta,
                                                 float* __restrict__ out,
                                                 int ntok) {
    __shared__ float ln_s[8][32];
    __shared__ float ln_ss[8][32];

    const int t    = threadIdx.x;
    const int w    = t >> 6;        // wave 0..7
    const int l    = t & 63;
    const int lo4  = l & 15;
    const int hi2  = l >> 4;        // 0..3
    const int tok0 = blockIdx.x << 5;

    f32x4 acc[2][8];
#pragma unroll
    for (int m2 = 0; m2 < 2; ++m2)
#pragma unroll
        for (int nf = 0; nf < 8; ++nf) {
            f32x4 z = {0.f, 0.f, 0.f, 0.f};
            acc[m2][nf] = z;
        }

    const unsigned short* Abase = A + ((size_t)tok0 << 8);

#pragma unroll
    for (int ks = 0; ks < 8; ++ks) {
        short8 af[2];
#pragma unroll
        for (int m2 = 0; m2 < 2; ++m2) {
            const int row = (m2 << 4) + lo4;
            af[m2] = *(const short8*)(Abase + ((size_t)row << 8) + (ks << 5) + (hi2 << 3));
        }
#pragma unroll
        for (int nf = 0; nf < 8; ++nf) {
            const int nfg = (w << 3) + nf;
            const uint4 bv = wb[(size_t)((nfg << 3) + ks) * 64 + l];
            const short8 bfr = __builtin_bit_cast(short8, bv);
            acc[0][nf] = __builtin_amdgcn_mfma_f32_16x16x32_bf16(af[0], bfr, acc[0][nf], 0, 0, 0);
            acc[1][nf] = __builtin_amdgcn_mfma_f32_16x16x32_bf16(af[1], bfr, acc[1][nf], 0, 0, 0);
        }
    }

    // ---- epilogue: +bias, per-token stats (token slot q = m2*4 + r) ----
    float s_[8], ss_[8];
#pragma unroll
    for (int q = 0; q < 8; ++q) { s_[q] = 0.f; ss_[q] = 0.f; }

#pragma unroll
    for (int nf = 0; nf < 8; ++nf) {
        const int col = (w << 7) + (nf << 4) + lo4;
        const float bu = b_up[col];
#pragma unroll
        for (int m2 = 0; m2 < 2; ++m2) {
            f32x4 v = acc[m2][nf];
            v.x += bu; v.y += bu; v.z += bu; v.w += bu;
            acc[m2][nf] = v;
            const int q0 = m2 * 4;
            s_[q0 + 0] += v.x; ss_[q0 + 0] += v.x * v.x;
            s_[q0 + 1] += v.y; ss_[q0 + 1] += v.y * v.y;
            s_[q0 + 2] += v.z; ss_[q0 + 2] += v.z * v.z;
            s_[q0 + 3] += v.w; ss_[q0 + 3] += v.w * v.w;
        }
    }
#pragma unroll
    for (int off = 1; off < 16; off <<= 1)
#pragma unroll
        for (int q = 0; q < 8; ++q) {
            s_[q]  += __shfl_xor(s_[q], off);
            ss_[q] += __shfl_xor(ss_[q], off);
        }
    if (lo4 == 0) {
#pragma unroll
        for (int q = 0; q < 8; ++q) {
            const int tl = (q >> 2) * 16 + hi2 * 4 + (q & 3);
            ln_s[w][tl]  = s_[q];
            ln_ss[w][tl] = ss_[q];
        }
    }
    __syncthreads();

    float mu_[8], inv_[8];
#pragma unroll
    for (int q = 0; q < 8; ++q) {
        const int tl = (q >> 2) * 16 + hi2 * 4 + (q & 3);
        float S = 0.f, SS = 0.f;
#pragma unroll
        for (int ww = 0; ww < 8; ++ww) { S += ln_s[ww][tl]; SS += ln_ss[ww][tl]; }
        const float mu  = S * (1.f / DDIM);
        const float var = SS * (1.f / DDIM) - mu * mu;
        mu_[q]  = mu;
        inv_[q] = rsqrtf(var + LN_EPS);
    }

    // ---- write out ----
#pragma unroll
    for (int nf = 0; nf < 8; ++nf) {
        const int col = (w << 7) + (nf << 4) + lo4;
        const float g  = gamma[col];
        const float bb = beta[col];
#pragma unroll
        for (int m2 = 0; m2 < 2; ++m2) {
            const f32x4 v = acc[m2][nf];
#pragma unroll
            for (int r = 0; r < 4; ++r) {
                const int q   = m2 * 4 + r;
                const int tl  = m2 * 16 + hi2 * 4 + r;
                const int tok = tok0 + tl;
                if (tok < ntok)
                    out[(size_t)tok * DDIM + col] = (v[r] - mu_[q]) * inv_[q] * g + bb;
            }
        }
    }
}

// ---------------------------------------------------------------------------
extern "C" void kernel_launch(void* const* d_in, const int* in_sizes, int n_in,
                              void* d_out, int out_size, void* d_ws, size_t ws_size,
                              hipStream_t stream) {
    const int*   ids   = (const int*)  d_in[0];
    const float* bt    = (const float*)d_in[1];
    const float* pe    = (const float*)d_in[2];
    const float* W     = (const float*)d_in[3];
    const float* b_up  = (const float*)d_in[4];
    const float* gamma = (const float*)d_in[5];
    const float* beta  = (const float*)d_in[6];
    float* out = (float*)d_out;

    const int ntok = in_sizes[0] / PP;   // B*S = 16384

    char* ws = (char*)d_ws;
    unsigned short* t2b = (unsigned short*)(ws);        // 2 MB
    uint4*          wbb = (uint4*)(ws + (2 << 20));     // 512 KB
    unsigned short* Abf = (unsigned short*)(ws + (3 << 20)); // ntok*256*2 = 8 MB
    uint2*          Aq  = (uint2*)Abf;

    hipLaunchKernelGGL(k_prep, dim3(640), dim3(256), 0, stream, bt, pe, W, t2b, wbb);
    hipLaunchKernelGGL(k_gather, dim3((ntok + 3) / 4), dim3(256), 0, stream,
                       ids, t2b, Aq, ntok);
    hipLaunchKernelGGL(k_gemm, dim3((ntok + 31) / 32), dim3(512), 0, stream,
                       Abf, wbb, b_up, gamma, beta, out, ntok);
}

// Round 4
// 89.326 us; speedup vs baseline: 1.0094x; 1.0094x over previous
//
#include <hip/hip_runtime.h>
#include <stdint.h>

#define PP     16
#define LRDIM  256
#define DDIM   1024
#define LN_EPS 1e-5f

typedef __attribute__((ext_vector_type(8))) short  short8;
typedef __attribute__((ext_vector_type(4))) float  f32x4;

__device__ __forceinline__ uint32_t bf16_rne(float f) {
    uint32_t u = __builtin_bit_cast(uint32_t, f);
    return (u + 0x7fffu + ((u >> 16) & 1u)) >> 16;
}
__device__ __forceinline__ float bf_lo(uint32_t u) {
    return __builtin_bit_cast(float, u << 16);
}
__device__ __forceinline__ float bf_hi(uint32_t u) {
    return __builtin_bit_cast(float, u & 0xffff0000u);
}

// ---------------------------------------------------------------------------
// K1 fused prep.
// blocks [0,512):  table2b[p][c][j] = bf16(sum_i pe[p][i][j] * bt[c][i])
// blocks [512,640): repack W_up [D][LR] f32 -> bf16 MFMA B-fragments:
//                  wb[(nfg*8+ks)*64+lane] = W[nfg*16+(l&15)][ks*32+(l>>4)*8+..7]
// ---------------------------------------------------------------------------
__global__ __launch_bounds__(256) void k_prep(const float* __restrict__ bt,
                                              const float* __restrict__ pe,
                                              const float* __restrict__ W,
                                              unsigned short* __restrict__ t2b,
                                              uint4* __restrict__ wb) {
    if (blockIdx.x < 512) {
        const int p  = blockIdx.x >> 5;          // 0..15
        const int c0 = (blockIdx.x & 31) << 3;   // 0..248
        const int j  = threadIdx.x;
        const float* pep = pe + (size_t)p * LRDIM * LRDIM;
        float a[8];
#pragma unroll
        for (int r = 0; r < 8; ++r) a[r] = 0.f;
#pragma unroll 4
        for (int i = 0; i < LRDIM; ++i) {
            const float v = pep[i * LRDIM + j];          // coalesced across j
#pragma unroll
            for (int r = 0; r < 8; ++r)                   // uniform -> s_loads
                a[r] = fmaf(v, bt[(c0 + r) * LRDIM + i], a[r]);
        }
#pragma unroll
        for (int r = 0; r < 8; ++r)
            t2b[(size_t)((p << 8) + c0 + r) * LRDIM + j] =
                (unsigned short)bf16_rne(a[r]);
    } else {
        const int gt  = (blockIdx.x - 512) * 256 + threadIdx.x;  // 0..32767
        const int l   = gt & 63;
        const int ks  = (gt >> 6) & 7;
        const int nfg = gt >> 9;                                  // 0..63
        const int n   = nfg * 16 + (l & 15);
        const int k   = ks * 32 + (l >> 4) * 8;
        const float* src = W + (size_t)n * LRDIM + k;
        uint32_t r[4];
#pragma unroll
        for (int q = 0; q < 4; ++q) {
            const uint32_t lo = bf16_rne(src[2 * q + 0]);
            const uint32_t hi = bf16_rne(src[2 * q + 1]);
            r[q] = lo | (hi << 16);
        }
        wb[gt] = make_uint4(r[0], r[1], r[2], r[3]);
    }
}

// ---------------------------------------------------------------------------
// K2: gather-sum. One wave per token; lane owns lr = 4l..4l+3.
// A[tok][256] bf16 out (uint2 per lane). 16 independent masked loads/lane.
// ---------------------------------------------------------------------------
__global__ __launch_bounds__(256) void k_gather(const int* __restrict__ ids,
                                                const unsigned short* __restrict__ t2b,
                                                uint2* __restrict__ Aq,
                                                int ntok) {
    const int wid = (blockIdx.x << 2) + (threadIdx.x >> 6);
    const int l   = threadIdx.x & 63;
    if (wid >= ntok) return;

    const int myid = (l < PP) ? ids[(size_t)wid * PP + l] : -1;

    float a0 = 0.f, a1 = 0.f, a2 = 0.f, a3 = 0.f;
#pragma unroll
    for (int p = 0; p < PP; ++p) {
        const int   id  = __shfl(myid, p);
        const float msk = (id >= 0) ? 1.f : 0.f;
        const uint2 v = *(const uint2*)(t2b +
                          ((size_t)((p << 8) + (id & 255)) << 8) + (l << 2));
        a0 = fmaf(msk, bf_lo(v.x), a0);
        a1 = fmaf(msk, bf_hi(v.x), a1);
        a2 = fmaf(msk, bf_lo(v.y), a2);
        a3 = fmaf(msk, bf_hi(v.y), a3);
    }
    uint2 pk;
    pk.x = bf16_rne(a0) | (bf16_rne(a1) << 16);
    pk.y = bf16_rne(a2) | (bf16_rne(a3) << 16);
    Aq[(size_t)wid * 64 + l] = pk;
}

// ---------------------------------------------------------------------------
// K3: MFMA GEMM + fused bias/LN.
// Block = 256 thr (4 waves), 16 tokens x N=1024; wave w owns cols
// [w*256, w*256+256) -> acc[16] (64 VGPR). A tile (8 KB) in XOR-swizzled LDS.
// B from prepacked wb (L2), ping-pong prefetched 4 fragments deep.
// __launch_bounds__(256,4): 4 blocks/CU, VGPR cap 128 -> no spill (acc 64 +
// b-buffers 32 + af 4 + addr ~12).
// ---------------------------------------------------------------------------
__global__ __launch_bounds__(256, 4) void k_gemm(const unsigned short* __restrict__ A,
                                                 const uint4* __restrict__ wb,
                                                 const float* __restrict__ b_up,
                                                 const float* __restrict__ gamma,
                                                 const float* __restrict__ beta,
                                                 float* __restrict__ out,
                                                 int ntok) {
    __shared__ __align__(16) unsigned char As[16 * 512];   // 8 KB swizzled A
    __shared__ float ln_s[4][16];
    __shared__ float ln_ss[4][16];

    const int t    = threadIdx.x;
    const int w    = t >> 6;        // wave 0..3
    const int l    = t & 63;
    const int lo4  = l & 15;
    const int hi2  = l >> 4;        // 0..3
    const int tok0 = blockIdx.x << 4;

    // ---- stage A tile: thread t -> row t>>4, two 16B chunks ----
    {
        const int r = t >> 4;       // 0..15
        const int c = t & 15;       // 0..15 (32B chunks)
        const uint4* asrc = (const uint4*)(A + ((size_t)(tok0 + r) << 8)) + (c << 1);
        const uint4 v0 = asrc[0];
        const uint4 v1 = asrc[1];
        const int sw = (r & 7) << 4;
        *(uint4*)(As + (r << 9) + (((c << 5)     ) ^ sw)) = v0;
        *(uint4*)(As + (r << 9) + (((c << 5) + 16) ^ sw)) = v1;
    }
    __syncthreads();

    // ---- MFMA: acc[nf], nf = 0..15 over K=256 in 8 k-steps ----
    f32x4 acc[16];
#pragma unroll
    for (int nf = 0; nf < 16; ++nf) {
        f32x4 z = {0.f, 0.f, 0.f, 0.f};
        acc[nf] = z;
    }

    // wb index: (nfg*8 + ks)*64 + l, nfg = w*16 + nf
    const uint4* wp = wb + ((size_t)w << 13) + l;
    const int swz = (lo4 & 7) << 4;

    uint4 bA[4], bB[4];
#pragma unroll
    for (int h = 0; h < 4; ++h) bA[h] = wp[h * 512];

#pragma unroll
    for (int ks = 0; ks < 8; ++ks) {
        const short8 af = *(const short8*)(As + (lo4 << 9) +
                                           (((ks << 6) + (hi2 << 4)) ^ swz));
#pragma unroll
        for (int g = 0; g < 4; ++g) {
            const int gn   = (g + 1) & 3;
            const int kn   = (g == 3) ? ks + 1 : ks;
            const bool last = (ks == 7) && (g == 3);
            if ((g & 1) == 0) {
                if (!last) {
#pragma unroll
                    for (int h = 0; h < 4; ++h)
                        bB[h] = wp[(gn * 4 + h) * 512 + kn * 64];
                }
#pragma unroll
                for (int h = 0; h < 4; ++h)
                    acc[g * 4 + h] = __builtin_amdgcn_mfma_f32_16x16x32_bf16(
                        af, __builtin_bit_cast(short8, bA[h]), acc[g * 4 + h], 0, 0, 0);
            } else {
                if (!last) {
#pragma unroll
                    for (int h = 0; h < 4; ++h)
                        bA[h] = wp[(gn * 4 + h) * 512 + kn * 64];
                }
#pragma unroll
                for (int h = 0; h < 4; ++h)
                    acc[g * 4 + h] = __builtin_amdgcn_mfma_f32_16x16x32_bf16(
                        af, __builtin_bit_cast(short8, bB[h]), acc[g * 4 + h], 0, 0, 0);
            }
        }
    }

    // ---- epilogue: +bias, per-token stats (token tl = hi2*4 + r) ----
    float s_[4], ss_[4];
#pragma unroll
    for (int q = 0; q < 4; ++q) { s_[q] = 0.f; ss_[q] = 0.f; }

#pragma unroll
    for (int nf = 0; nf < 16; ++nf) {
        const int col = (w << 8) + (nf << 4) + lo4;
        const float bu = b_up[col];
        f32x4 v = acc[nf];
        v.x += bu; v.y += bu; v.z += bu; v.w += bu;
        acc[nf] = v;
        s_[0] += v.x; ss_[0] += v.x * v.x;
        s_[1] += v.y; ss_[1] += v.y * v.y;
        s_[2] += v.z; ss_[2] += v.z * v.z;
        s_[3] += v.w; ss_[3] += v.w * v.w;
    }
#pragma unroll
    for (int off = 1; off < 16; off <<= 1)
#pragma unroll
        for (int q = 0; q < 4; ++q) {
            s_[q]  += __shfl_xor(s_[q], off);
            ss_[q] += __shfl_xor(ss_[q], off);
        }
    if (lo4 == 0) {
#pragma unroll
        for (int q = 0; q < 4; ++q) {
            ln_s[w][hi2 * 4 + q]  = s_[q];
            ln_ss[w][hi2 * 4 + q] = ss_[q];
        }
    }
    __syncthreads();

    float mu_[4], inv_[4];
#pragma unroll
    for (int q = 0; q < 4; ++q) {
        const int tl = hi2 * 4 + q;
        float S = 0.f, SS = 0.f;
#pragma unroll
        for (int ww = 0; ww < 4; ++ww) { S += ln_s[ww][tl]; SS += ln_ss[ww][tl]; }
        const float mu  = S * (1.f / DDIM);
        const float var = SS * (1.f / DDIM) - mu * mu;
        mu_[q]  = mu;
        inv_[q] = rsqrtf(var + LN_EPS);
    }

    // ---- write out ----
#pragma unroll
    for (int nf = 0; nf < 16; ++nf) {
        const int col = (w << 8) + (nf << 4) + lo4;
        const float g  = gamma[col];
        const float bb = beta[col];
        const f32x4 v = acc[nf];
#pragma unroll
        for (int r = 0; r < 4; ++r) {
            const int tok = tok0 + hi2 * 4 + r;
            if (tok < ntok)
                out[(size_t)tok * DDIM + col] = (v[r] - mu_[r]) * inv_[r] * g + bb;
        }
    }
}

// ---------------------------------------------------------------------------
extern "C" void kernel_launch(void* const* d_in, const int* in_sizes, int n_in,
                              void* d_out, int out_size, void* d_ws, size_t ws_size,
                              hipStream_t stream) {
    const int*   ids   = (const int*)  d_in[0];
    const float* bt    = (const float*)d_in[1];
    const float* pe    = (const float*)d_in[2];
    const float* W     = (const float*)d_in[3];
    const float* b_up  = (const float*)d_in[4];
    const float* gamma = (const float*)d_in[5];
    const float* beta  = (const float*)d_in[6];
    float* out = (float*)d_out;

    const int ntok = in_sizes[0] / PP;   // B*S = 16384

    char* ws = (char*)d_ws;
    unsigned short* t2b = (unsigned short*)(ws);        // 2 MB
    uint4*          wbb = (uint4*)(ws + (2 << 20));     // 512 KB
    unsigned short* Abf = (unsigned short*)(ws + (3 << 20)); // ntok*256*2 = 8 MB
    uint2*          Aq  = (uint2*)Abf;

    hipLaunchKernelGGL(k_prep, dim3(640), dim3(256), 0, stream, bt, pe, W, t2b, wbb);
    hipLaunchKernelGGL(k_gather, dim3((ntok + 3) / 4), dim3(256), 0, stream,
                       ids, t2b, Aq, ntok);
    hipLaunchKernelGGL(k_gemm, dim3((ntok + 15) / 16), dim3(256), 0, stream,
                       Abf, wbb, b_up, gamma, beta, out, ntok);
}

// Round 5
// 79.067 us; speedup vs baseline: 1.1404x; 1.1298x over previous
//
#include <hip/hip_runtime.h>
#include <stdint.h>

#define PP     16
#define LRDIM  256
#define DDIM   1024
#define LN_EPS 1e-5f

typedef __attribute__((ext_vector_type(8))) short  short8;
typedef __attribute__((ext_vector_type(4))) float  f32x4;

__device__ __forceinline__ uint32_t bf16_rne(float f) {
    uint32_t u = __builtin_bit_cast(uint32_t, f);
    return (u + 0x7fffu + ((u >> 16) & 1u)) >> 16;
}
__device__ __forceinline__ float bf_lo(uint32_t u) {
    return __builtin_bit_cast(float, u << 16);
}
__device__ __forceinline__ float bf_hi(uint32_t u) {
    return __builtin_bit_cast(float, u & 0xffff0000u);
}

// ---------------------------------------------------------------------------
// K1 fused prep.
// blocks [0,256):  table2b[p][c][j] = bf16(sum_i pe[p][i][j] * bt[c][i]),
//                  16 c-rows per block; bt tile staged in LDS (broadcast reads)
// blocks [256,384): repack W_up [D][LR] f32 -> bf16 MFMA B-fragments:
//                  wb[(nfg*8+ks)*64+lane] = W[nfg*16+(l&15)][ks*32+(l>>4)*8+..7]
// ---------------------------------------------------------------------------
__global__ __launch_bounds__(256) void k_prep(const float* __restrict__ bt,
                                              const float* __restrict__ pe,
                                              const float* __restrict__ W,
                                              unsigned short* __restrict__ t2b,
                                              uint4* __restrict__ wb) {
    if (blockIdx.x < 256) {
        const int p  = blockIdx.x >> 4;          // 0..15
        const int c0 = (blockIdx.x & 15) << 4;   // 0..240
        const int j  = threadIdx.x;
        __shared__ float sbt[16][LRDIM];
#pragma unroll
        for (int r = 0; r < 16; ++r)
            sbt[r][j] = bt[(size_t)(c0 + r) * LRDIM + j];
        __syncthreads();

        const float* pep = pe + (size_t)p * LRDIM * LRDIM;
        float a[16];
#pragma unroll
        for (int r = 0; r < 16; ++r) a[r] = 0.f;
#pragma unroll 4
        for (int i = 0; i < LRDIM; ++i) {
            const float v = pep[i * LRDIM + j];          // coalesced across j
#pragma unroll
            for (int r = 0; r < 16; ++r)                  // LDS broadcast
                a[r] = fmaf(v, sbt[r][i], a[r]);
        }
#pragma unroll
        for (int r = 0; r < 16; ++r)
            t2b[(size_t)((p << 8) + c0 + r) * LRDIM + j] =
                (unsigned short)bf16_rne(a[r]);
    } else {
        const int gt  = (blockIdx.x - 256) * 256 + threadIdx.x;  // 0..32767
        const int l   = gt & 63;
        const int ks  = (gt >> 6) & 7;
        const int nfg = gt >> 9;                                  // 0..63
        const int n   = nfg * 16 + (l & 15);
        const int k   = ks * 32 + (l >> 4) * 8;
        const float* src = W + (size_t)n * LRDIM + k;
        uint32_t r[4];
#pragma unroll
        for (int q = 0; q < 4; ++q) {
            const uint32_t lo = bf16_rne(src[2 * q + 0]);
            const uint32_t hi = bf16_rne(src[2 * q + 1]);
            r[q] = lo | (hi << 16);
        }
        wb[gt] = make_uint4(r[0], r[1], r[2], r[3]);
    }
}

// ---------------------------------------------------------------------------
// K2: gather-sum. One wave per token; lane owns lr = 4l..4l+3.
// A[tok][256] bf16 out (uint2 per lane). 16 independent masked loads/lane.
// ---------------------------------------------------------------------------
__global__ __launch_bounds__(256) void k_gather(const int* __restrict__ ids,
                                                const unsigned short* __restrict__ t2b,
                                                uint2* __restrict__ Aq,
                                                int ntok) {
    const int wid = (blockIdx.x << 2) + (threadIdx.x >> 6);
    const int l   = threadIdx.x & 63;
    if (wid >= ntok) return;

    const int myid = (l < PP) ? ids[(size_t)wid * PP + l] : -1;

    float a0 = 0.f, a1 = 0.f, a2 = 0.f, a3 = 0.f;
#pragma unroll
    for (int p = 0; p < PP; ++p) {
        const int   id  = __shfl(myid, p);
        const float msk = (id >= 0) ? 1.f : 0.f;
        const uint2 v = *(const uint2*)(t2b +
                          ((size_t)((p << 8) + (id & 255)) << 8) + (l << 2));
        a0 = fmaf(msk, bf_lo(v.x), a0);
        a1 = fmaf(msk, bf_hi(v.x), a1);
        a2 = fmaf(msk, bf_lo(v.y), a2);
        a3 = fmaf(msk, bf_hi(v.y), a3);
    }
    uint2 pk;
    pk.x = bf16_rne(a0) | (bf16_rne(a1) << 16);
    pk.y = bf16_rne(a2) | (bf16_rne(a3) << 16);
    Aq[(size_t)wid * 64 + l] = pk;
}

// ---------------------------------------------------------------------------
// K3: MFMA GEMM + fused bias/LN.
// Block = 512 thr (8 waves), 32 tokens x N=1024. Wave w owns N-slice
// [w*128, w*128+128): acc[m2][nf] = 2 x 8 f32x4 = 64 regs (AGPR).
// A-fragments loaded straight from L2; B from prepacked wb (L2).
// __launch_bounds__(512,2): unified-file cap = 512/2 = 256 regs/wave ->
// acc(64 AGPR) + ~120 arch VGPR fits with big margin; NO spill.
// (Rounds 3&4 failed here: (…,4) caps at 128 total incl. AGPRs -> scratch.)
// ---------------------------------------------------------------------------
__global__ __launch_bounds__(512, 2) void k_gemm(const unsigned short* __restrict__ A,
                                                 const uint4* __restrict__ wb,
                                                 const float* __restrict__ b_up,
                                                 const float* __restrict__ gamma,
                                                 const float* __restrict__ beta,
                                                 float* __restrict__ out,
                                                 int ntok) {
    __shared__ float ln_s[8][32];
    __shared__ float ln_ss[8][32];

    const int t    = threadIdx.x;
    const int w    = t >> 6;        // wave 0..7
    const int l    = t & 63;
    const int lo4  = l & 15;
    const int hi2  = l >> 4;        // 0..3
    const int tok0 = blockIdx.x << 5;

    f32x4 acc[2][8];
#pragma unroll
    for (int m2 = 0; m2 < 2; ++m2)
#pragma unroll
        for (int nf = 0; nf < 8; ++nf) {
            f32x4 z = {0.f, 0.f, 0.f, 0.f};
            acc[m2][nf] = z;
        }

    const unsigned short* Abase = A + ((size_t)tok0 << 8);

#pragma unroll
    for (int ks = 0; ks < 8; ++ks) {
        short8 af[2];
#pragma unroll
        for (int m2 = 0; m2 < 2; ++m2) {
            const int row = (m2 << 4) + lo4;
            af[m2] = *(const short8*)(Abase + ((size_t)row << 8) + (ks << 5) + (hi2 << 3));
        }
#pragma unroll
        for (int nf = 0; nf < 8; ++nf) {
            const int nfg = (w << 3) + nf;
            const uint4 bv = wb[(size_t)((nfg << 3) + ks) * 64 + l];
            const short8 bfr = __builtin_bit_cast(short8, bv);
            acc[0][nf] = __builtin_amdgcn_mfma_f32_16x16x32_bf16(af[0], bfr, acc[0][nf], 0, 0, 0);
            acc[1][nf] = __builtin_amdgcn_mfma_f32_16x16x32_bf16(af[1], bfr, acc[1][nf], 0, 0, 0);
        }
    }

    // ---- epilogue: +bias, per-token stats (token slot q = m2*4 + r) ----
    float s_[8], ss_[8];
#pragma unroll
    for (int q = 0; q < 8; ++q) { s_[q] = 0.f; ss_[q] = 0.f; }

#pragma unroll
    for (int nf = 0; nf < 8; ++nf) {
        const int col = (w << 7) + (nf << 4) + lo4;
        const float bu = b_up[col];
#pragma unroll
        for (int m2 = 0; m2 < 2; ++m2) {
            f32x4 v = acc[m2][nf];
            v.x += bu; v.y += bu; v.z += bu; v.w += bu;
            acc[m2][nf] = v;
            const int q0 = m2 * 4;
            s_[q0 + 0] += v.x; ss_[q0 + 0] += v.x * v.x;
            s_[q0 + 1] += v.y; ss_[q0 + 1] += v.y * v.y;
            s_[q0 + 2] += v.z; ss_[q0 + 2] += v.z * v.z;
            s_[q0 + 3] += v.w; ss_[q0 + 3] += v.w * v.w;
        }
    }
#pragma unroll
    for (int off = 1; off < 16; off <<= 1)
#pragma unroll
        for (int q = 0; q < 8; ++q) {
            s_[q]  += __shfl_xor(s_[q], off);
            ss_[q] += __shfl_xor(ss_[q], off);
        }
    if (lo4 == 0) {
#pragma unroll
        for (int q = 0; q < 8; ++q) {
            const int tl = (q >> 2) * 16 + hi2 * 4 + (q & 3);
            ln_s[w][tl]  = s_[q];
            ln_ss[w][tl] = ss_[q];
        }
    }
    __syncthreads();

    float mu_[8], inv_[8];
#pragma unroll
    for (int q = 0; q < 8; ++q) {
        const int tl = (q >> 2) * 16 + hi2 * 4 + (q & 3);
        float S = 0.f, SS = 0.f;
#pragma unroll
        for (int ww = 0; ww < 8; ++ww) { S += ln_s[ww][tl]; SS += ln_ss[ww][tl]; }
        const float mu  = S * (1.f / DDIM);
        const float var = SS * (1.f / DDIM) - mu * mu;
        mu_[q]  = mu;
        inv_[q] = rsqrtf(var + LN_EPS);
    }

    // ---- write out ----
#pragma unroll
    for (int nf = 0; nf < 8; ++nf) {
        const int col = (w << 7) + (nf << 4) + lo4;
        const float g  = gamma[col];
        const float bb = beta[col];
#pragma unroll
        for (int m2 = 0; m2 < 2; ++m2) {
            const f32x4 v = acc[m2][nf];
#pragma unroll
            for (int r = 0; r < 4; ++r) {
                const int q   = m2 * 4 + r;
                const int tl  = m2 * 16 + hi2 * 4 + r;
                const int tok = tok0 + tl;
                if (tok < ntok)
                    out[(size_t)tok * DDIM + col] = (v[r] - mu_[q]) * inv_[q] * g + bb;
            }
        }
    }
}

// ---------------------------------------------------------------------------
extern "C" void kernel_launch(void* const* d_in, const int* in_sizes, int n_in,
                              void* d_out, int out_size, void* d_ws, size_t ws_size,
                              hipStream_t stream) {
    const int*   ids   = (const int*)  d_in[0];
    const float* bt    = (const float*)d_in[1];
    const float* pe    = (const float*)d_in[2];
    const float* W     = (const float*)d_in[3];
    const float* b_up  = (const float*)d_in[4];
    const float* gamma = (const float*)d_in[5];
    const float* beta  = (const float*)d_in[6];
    float* out = (float*)d_out;

    const int ntok = in_sizes[0] / PP;   // B*S = 16384

    char* ws = (char*)d_ws;
    unsigned short* t2b = (unsigned short*)(ws);        // 2 MB
    uint4*          wbb = (uint4*)(ws + (2 << 20));     // 512 KB
    unsigned short* Abf = (unsigned short*)(ws + (3 << 20)); // ntok*256*2 = 8 MB
    uint2*          Aq  = (uint2*)Abf;

    hipLaunchKernelGGL(k_prep, dim3(384), dim3(256), 0, stream, bt, pe, W, t2b, wbb);
    hipLaunchKernelGGL(k_gather, dim3((ntok + 3) / 4), dim3(256), 0, stream,
                       ids, t2b, Aq, ntok);
    hipLaunchKernelGGL(k_gemm, dim3((ntok + 31) / 32), dim3(512), 0, stream,
                       Abf, wbb, b_up, gamma, beta, out, ntok);
}